// Round 1
// baseline (11924.916 us; speedup 1.0000x reference)
//
#include <hip/hip_runtime.h>
#include <math.h>

// Problem constants (4, 19, 512, 512) fp32
#define BB 4
#define CC 19
#define HH 512
#define WW 512
#define NSLICE (BB * CC)        // 76
#define SLICE  (HH * WW)        // 262144
#define W4     (WW / 4)         // 128 float4 per row
#define EPS    1e-12f

// ---------------------------------------------------------------------------
// init: cur0 = -x, border (i==0, i==511, j==0, j==511) = 1.0
// one float4 per thread
__global__ void init_kernel(const float* __restrict__ x, float* __restrict__ cur) {
    int t = blockIdx.x * blockDim.x + threadIdx.x;   // over NSLICE*SLICE/4
    const float4* x4 = (const float4*)x;
    float4* c4 = (float4*)cur;
    float4 v = x4[t];
    int pix = t << 2;
    int s = pix & (SLICE - 1);
    int i = s >> 9;          // row
    int j0 = s & 511;        // first col of this float4
    float4 o;
    o.x = -v.x; o.y = -v.y; o.z = -v.z; o.w = -v.w;
    if (i == 0 || i == HH - 1) {
        o.x = 1.0f; o.y = 1.0f; o.z = 1.0f; o.w = 1.0f;
    } else {
        if (j0 == 0)        o.x = 1.0f;
        if (j0 == WW - 4)   o.w = 1.0f;
    }
    c4[t] = o;
}

// ---------------------------------------------------------------------------
// one fused step: out = maxpool3x3_same(in, pad=-inf) * x
// each thread computes 4 consecutive pixels in a row (float4)
__global__ void step_kernel(const float* __restrict__ in,
                            const float* __restrict__ x,
                            float* __restrict__ out) {
    int t = blockIdx.x * blockDim.x + threadIdx.x;   // over NSLICE * HH * W4
    int j4 = t & (W4 - 1);
    int i  = (t >> 7) & (HH - 1);
    int bc = t >> 16;                                 // 512*128 = 65536 = 2^16
    int j0 = j4 << 2;

    const float* base = in + (size_t)bc * SLICE;
    const float NEG = -INFINITY;

    float v[3][6];
#pragma unroll
    for (int r = 0; r < 3; ++r) {
        int ii = i + r - 1;
        if (ii < 0 || ii >= HH) {
#pragma unroll
            for (int k = 0; k < 6; ++k) v[r][k] = NEG;
        } else {
            const float* row = base + ii * WW + j0;
            float4 c = *(const float4*)row;
            v[r][1] = c.x; v[r][2] = c.y; v[r][3] = c.z; v[r][4] = c.w;
            v[r][0] = (j0 > 0)      ? row[-1] : NEG;
            v[r][5] = (j0 + 4 < WW) ? row[4]  : NEG;
        }
    }

    // horizontal 3-max per row, then vertical 3-max
    float h[3][4];
#pragma unroll
    for (int r = 0; r < 3; ++r) {
#pragma unroll
        for (int k = 0; k < 4; ++k)
            h[r][k] = fmaxf(fmaxf(v[r][k], v[r][k + 1]), v[r][k + 2]);
    }
    float4 m;
    m.x = fmaxf(fmaxf(h[0][0], h[1][0]), h[2][0]);
    m.y = fmaxf(fmaxf(h[0][1], h[1][1]), h[2][1]);
    m.z = fmaxf(fmaxf(h[0][2], h[1][2]), h[2][2]);
    m.w = fmaxf(fmaxf(h[0][3], h[1][3]), h[2][3]);

    const float4 xv = *(const float4*)(x + (size_t)bc * SLICE + i * WW + j0);
    float4 o;
    o.x = m.x * xv.x; o.y = m.y * xv.y; o.z = m.z * xv.z; o.w = m.w * xv.w;
    *(float4*)(out + (size_t)bc * SLICE + i * WW + j0) = o;
}

// ---------------------------------------------------------------------------
// final: norm over channel dim (19), out = cur * x / max(||cur||_2, eps)
// each thread owns one (b, i, j0..j0+3) float4 column-group across channels
__global__ void norm_kernel(const float* __restrict__ cur,
                            const float* __restrict__ x,
                            float* __restrict__ out) {
    int t = blockIdx.x * blockDim.x + threadIdx.x;   // over BB * HH * W4 = 262144
    int j4 = t & (W4 - 1);
    int i  = (t >> 7) & (HH - 1);
    int b  = t >> 16;
    size_t off = (size_t)b * CC * SLICE + (size_t)i * WW + (j4 << 2);

    float4 vals[CC];
    float sx = 0.f, sy = 0.f, sz = 0.f, sw = 0.f;
#pragma unroll
    for (int c = 0; c < CC; ++c) {
        float4 v = *(const float4*)(cur + off + (size_t)c * SLICE);
        vals[c] = v;
        sx += v.x * v.x; sy += v.y * v.y; sz += v.z * v.z; sw += v.w * v.w;
    }
    float4 r;
    r.x = 1.0f / fmaxf(sqrtf(sx), EPS);
    r.y = 1.0f / fmaxf(sqrtf(sy), EPS);
    r.z = 1.0f / fmaxf(sqrtf(sz), EPS);
    r.w = 1.0f / fmaxf(sqrtf(sw), EPS);
#pragma unroll
    for (int c = 0; c < CC; ++c) {
        float4 xv = *(const float4*)(x + off + (size_t)c * SLICE);
        float4 o;
        o.x = vals[c].x * xv.x * r.x;
        o.y = vals[c].y * xv.y * r.y;
        o.z = vals[c].z * xv.z * r.z;
        o.w = vals[c].w * xv.w * r.w;
        *(float4*)(out + off + (size_t)c * SLICE) = o;
    }
}

// ---------------------------------------------------------------------------
extern "C" void kernel_launch(void* const* d_in, const int* in_sizes, int n_in,
                              void* d_out, int out_size, void* d_ws, size_t ws_size,
                              hipStream_t stream) {
    const float* x = (const float*)d_in[0];
    float* out = (float*)d_out;
    float* ws  = (float*)d_ws;        // >= 4*19*512*512*4 = 79,691,776 B needed

    const int stepBlocks = NSLICE * HH * W4 / 256;   // 19456
    const int initBlocks = NSLICE * SLICE / 4 / 256; // 19456
    const int normBlocks = BB * HH * W4 / 256;       // 1024

    // ping-pong: a=ws, b=out. 256 steps (even) -> result back in ws.
    init_kernel<<<initBlocks, 256, 0, stream>>>(x, ws);
    float* a = ws;
    float* b = out;
    for (int it = 0; it < 256; ++it) {
        step_kernel<<<stepBlocks, 256, 0, stream>>>(a, x, b);
        float* tmp = a; a = b; b = tmp;
    }
    // a == ws now holds cur_256
    norm_kernel<<<normBlocks, 256, 0, stream>>>(ws, x, out);
}